// Round 18
// baseline (155.914 us; speedup 1.0000x reference)
//
#include <hip/hip_runtime.h>
#include <math.h>

// CriticGraphPolicy, MI355X (gfx950). Round 18.
// R17: phase0 blocking neutral. Model fix: MFMA-pipe mandatory busy ~20us
// (19.4 cyc/SIMD per 16x16x32, m06); measured MfmaUtil 21% matches -> mlp is
// a fill-factor problem. R15's 4-waves/SIMD test was confounded (thin waves +
// duplicated loads). R18 tests the untried cell: FAT waves x 4/SIMD x 1 round:
// 256 rows/block, 1024 thr (16 waves), K split 224/192, h1[256][228]=116.7KB
// (fits 160KB LDS, 1 block/CU), 256 blocks. Per-wave shape = R12.

#define BTOT   65536
#define XUM_OFF 655360ull        // xum offset in d_ws (frag img = 638,976 B)

// phase0 (+fused pack) -- unchanged from R17
#define PK_BLK  78
#define PH_THR  512
#define PH_ROWS 256
#define PH_BLK  (BTOT / PH_ROWS)
#define F1W 0
#define F1B 2112
#define F2W 2176
#define F2B 6272
#define F3W 6336
#define F3B 8384
#define W0_FLOATS 8416

// mlp
#define ML_THR  1024             // 16 waves
#define ML_ROWS 256
#define ML_BLK  (BTOT / ML_ROWS) // 256 = 1/CU, one round
#define H1S     228              // u16 stride: 456B rows -> 2-way banks

typedef float  f32x4 __attribute__((ext_vector_type(4)));
typedef __bf16 bf16x8 __attribute__((ext_vector_type(8)));
typedef unsigned short u16x8 __attribute__((ext_vector_type(8)));
typedef unsigned short u16x4 __attribute__((ext_vector_type(4)));
typedef unsigned int   u32x2 __attribute__((ext_vector_type(2)));

__device__ __forceinline__ unsigned short f2b(float f) {
  union { float f; unsigned int u; } v; v.f = f;
  return (unsigned short)((v.u + 0x7fffu + ((v.u >> 16) & 1u)) >> 16);
}
__device__ __forceinline__ float b2f(unsigned short u) {
  union { unsigned int u; float f; } v; v.u = ((unsigned int)u) << 16;
  return v.f;
}
__device__ __forceinline__ f32x4 MFMA(bf16x8 a, bf16x8 b, f32x4 c) {
  return __builtin_amdgcn_mfma_f32_16x16x32_bf16(a, b, c, 0, 0, 0);
}
__device__ __forceinline__ bf16x8 ld8(const unsigned short* p) {
  return __builtin_bit_cast(bf16x8, *(const u16x8*)p);
}
__device__ __forceinline__ float ftanh(float x) {
  float e = __builtin_amdgcn_exp2f(x * 2.885390081777927f);
  return (e - 1.0f) * __builtin_amdgcn_rcpf(e + 1.0f);
}

// ---------------- phase0 kernel (+fused fragment pack) -- R17 verbatim ------
struct P0 {
  const float* state; const float* action;
  const float* f1w; const float* f1b;
  const float* f2w; const float* f2b;
  const float* f3w; const float* f3b;
  const float* q1w1; const float* q1b1; const float* q1w2;
  const float* q2w1; const float* q2b1; const float* q2w2;
  unsigned short* ws;
  unsigned short* xum;
};

__global__ __launch_bounds__(PH_THR, 2) void phase0_kernel(P0 P) {
  __shared__ float w0[W0_FLOATS];
  __shared__ unsigned short hx[PH_ROWS * 68];
  const int tid = threadIdx.x;

  if (blockIdx.x < PK_BLK) {          // fragment pack path (R12 16x16 layout)
    const int gid = blockIdx.x * PH_THR + tid;
    const int lane = gid & 63, f = gid >> 6;
    const int q = f / 312, fl = f - q * 312;
    const float* w1 = q ? P.q2w1 : P.q1w1;
    const float* b1 = q ? P.q2b1 : P.q1b1;
    const float* w2 = q ? P.q2w2 : P.q1w2;
    int nt, ks; const bool isw1 = (fl < 52);
    if (isw1) { nt = fl >> 1; ks = fl & 1; }
    else      { int fl2 = fl - 52; nt = fl2 / 13; ks = fl2 - nt * 13; }
    const int col = nt * 16 + (lane & 15);
    const int k0  = ks * 32 + (lane >> 4) * 8;
    unsigned short v[8];
    #pragma unroll
    for (int j = 0; j < 8; ++j) {
      const int k = k0 + j;
      float x = 0.f;
      if (isw1) {
        if (col < 400) {
          if (k < 39) x = w1[(6 + k) * 400 + col];
          else if (k == 39) x = b1[col];
        }
      } else {
        if (k < 400 && col < 300) x = w2[k * 300 + col];
      }
      v[j] = f2b(x);
    }
    *(u16x8*)(P.ws + (size_t)f * 512 + lane * 8) = *(const u16x8*)v;
    return;
  }

  const int rid = tid >> 2, sub = tid & 3, j0 = sub * 16;
  const long g0 = (long)(blockIdx.x - PK_BLK) * PH_ROWS + rid;
  const long g1 = g0 + 128;

  for (int i = tid; i < 528;  i += PH_THR) *(f32x4*)(w0 + F1W + 4*i) = *(const f32x4*)(P.f1w + 4*i);
  for (int i = tid; i < 16;   i += PH_THR) *(f32x4*)(w0 + F1B + 4*i) = *(const f32x4*)(P.f1b + 4*i);
  for (int i = tid; i < 1024; i += PH_THR) *(f32x4*)(w0 + F2W + 4*i) = *(const f32x4*)(P.f2w + 4*i);
  for (int i = tid; i < 16;   i += PH_THR) *(f32x4*)(w0 + F2B + 4*i) = *(const f32x4*)(P.f2b + 4*i);
  for (int i = tid; i < 512;  i += PH_THR) *(f32x4*)(w0 + F3W + 4*i) = *(const f32x4*)(P.f3w + 4*i);
  for (int i = tid; i < 8;    i += PH_THR) *(f32x4*)(w0 + F3B + 4*i) = *(const f32x4*)(P.f3b + 4*i);

  {
    float sa0[33], sa1[33];
    {
      const float4* sp0 = (const float4*)(P.state + g0 * 32);
      const float4* sp1 = (const float4*)(P.state + g1 * 32);
      #pragma unroll
      for (int c = 0; c < 8; ++c) {
        float4 a = sp0[c], b = sp1[c];
        sa0[c*4+0] = a.x; sa0[c*4+1] = a.y; sa0[c*4+2] = a.z; sa0[c*4+3] = a.w;
        sa1[c*4+0] = b.x; sa1[c*4+1] = b.y; sa1[c*4+2] = b.z; sa1[c*4+3] = b.w;
      }
      sa0[32] = P.action[g0];
      sa1[32] = P.action[g1];
    }
    __syncthreads();
    float a0[16], a1[16];
    #pragma unroll
    for (int j = 0; j < 16; ++j) { a0[j] = w0[F1B + j0 + j]; a1[j] = a0[j]; }
    #pragma unroll 4
    for (int i = 0; i < 33; ++i) {
      const float s0 = sa0[i], s1 = sa1[i];
      const f32x4* wr = (const f32x4*)&w0[F1W + i * 64 + j0];
      #pragma unroll
      for (int c = 0; c < 4; ++c) {
        f32x4 wv = wr[c];
        #pragma unroll
        for (int u = 0; u < 4; ++u) {
          a0[c*4+u] += s0 * wv[u];
          a1[c*4+u] += s1 * wv[u];
        }
      }
    }
    float ss0 = 0.f, ss1 = 0.f;
    #pragma unroll
    for (int j = 0; j < 16; ++j) { ss0 += a0[j] * a0[j]; ss1 += a1[j] * a1[j]; }
    ss0 += __shfl_xor(ss0, 1, 64); ss0 += __shfl_xor(ss0, 2, 64);
    ss1 += __shfl_xor(ss1, 1, 64); ss1 += __shfl_xor(ss1, 2, 64);
    const float sc0 = 1.f / fmaxf(sqrtf(ss0), 1e-12f);
    const float sc1 = 1.f / fmaxf(sqrtf(ss1), 1e-12f);
    #pragma unroll
    for (int j = 0; j < 16; ++j) {
      hx[rid * 68 + j0 + j]         = f2b(ftanh(a0[j] * sc0));
      hx[(rid + 128) * 68 + j0 + j] = f2b(ftanh(a1[j] * sc1));
    }
  }
  __syncthreads();
  {
    float a0[16], a1[16];
    #pragma unroll
    for (int j = 0; j < 16; ++j) { a0[j] = w0[F2B + j0 + j]; a1[j] = a0[j]; }
    #pragma unroll 2
    for (int i0 = 0; i0 < 16; ++i0) {
      const u16x4 h0 = *(const u16x4*)&hx[rid * 68 + i0 * 4];
      const u16x4 h1v = *(const u16x4*)&hx[(rid + 128) * 68 + i0 * 4];
      #pragma unroll
      for (int u = 0; u < 4; ++u) {
        const float v0 = b2f(h0[u]), v1 = b2f(h1v[u]);
        const f32x4* wr = (const f32x4*)&w0[F2W + (i0 * 4 + u) * 64 + j0];
        #pragma unroll
        for (int c = 0; c < 4; ++c) {
          f32x4 wv = wr[c];
          #pragma unroll
          for (int t = 0; t < 4; ++t) {
            a0[c*4+t] += v0 * wv[t];
            a1[c*4+t] += v1 * wv[t];
          }
        }
      }
    }
    __syncthreads();
    #pragma unroll
    for (int j = 0; j < 16; ++j) {
      hx[rid * 68 + j0 + j]         = f2b(ftanh(a0[j]));
      hx[(rid + 128) * 68 + j0 + j] = f2b(ftanh(a1[j]));
    }
  }
  __syncthreads();
  const int j0m = sub * 8;
  float m0[8], m1[8];
  #pragma unroll
  for (int j = 0; j < 8; ++j) { m0[j] = w0[F3B + j0m + j]; m1[j] = m0[j]; }
  #pragma unroll 2
  for (int i0 = 0; i0 < 16; ++i0) {
    const u16x4 h0 = *(const u16x4*)&hx[rid * 68 + i0 * 4];
    const u16x4 h1v = *(const u16x4*)&hx[(rid + 128) * 68 + i0 * 4];
    #pragma unroll
    for (int u = 0; u < 4; ++u) {
      const float v0 = b2f(h0[u]), v1 = b2f(h1v[u]);
      const f32x4* wr = (const f32x4*)&w0[F3W + (i0 * 4 + u) * 32 + j0m];
      #pragma unroll
      for (int c = 0; c < 2; ++c) {
        f32x4 wv = wr[c];
        #pragma unroll
        for (int t = 0; t < 4; ++t) {
          m0[c*4+t] += v0 * wv[t];
          m1[c*4+t] += v1 * wv[t];
        }
      }
    }
  }
  float sm0 = 0.f, sm1 = 0.f;
  #pragma unroll
  for (int j = 0; j < 8; ++j) { sm0 += m0[j] * m0[j]; sm1 += m1[j] * m1[j]; }
  sm0 += __shfl_xor(sm0, 1, 64); sm0 += __shfl_xor(sm0, 2, 64);
  sm1 += __shfl_xor(sm1, 1, 64); sm1 += __shfl_xor(sm1, 2, 64);
  const float sc0 = 1.f / fmaxf(sqrtf(sm0), 1e-12f);
  const float sc1 = 1.f / fmaxf(sqrtf(sm1), 1e-12f);
  __syncthreads();
  #pragma unroll
  for (int j = 0; j < 8; ++j) {
    hx[rid * 68 + j0m + j]         = f2b(m0[j] * sc0);
    hx[(rid + 128) * 68 + j0m + j] = f2b(m1[j] * sc1);
  }
  __syncthreads();
  #pragma unroll
  for (int rr = 0; rr < 2; ++rr) {
    const long gr = rr ? g1 : g0;
    const int  lr = rid + rr * 128;
    float pos[3];
    pos[0] = P.state[gr * 32 + 0];
    pos[1] = P.state[gr * 32 + 1];
    pos[2] = P.state[gr * 32 + 2];
    const float act = P.action[gr];
    u16x8 v0, v1;
    #pragma unroll
    for (int t = 0; t < 16; ++t) {
      const int c = j0 + t;
      unsigned short u;
      if      (c < 3)  u = f2b(pos[c]);
      else if (c < 6)  u = f2b(pos[c - 3]);
      else if (c < 38) u = hx[lr * 68 + (c - 6)];
      else if (c == 38) u = f2b(act);
      else if (c == 39) u = 0x3f80;
      else              u = 0;
      if (t < 8) v0[t] = u; else v1[t - 8] = u;
    }
    unsigned short* dst = P.xum + (size_t)gr * 64 + j0;
    *(u16x8*)dst = v0;
    *(u16x8*)(dst + 8) = v1;
  }
}

// ---------------- mlp kernel: 256 rows, 16 fat waves, K-split ----------------
struct P1 {
  const unsigned short* img; const unsigned short* xum;
  const float* q1b2; const float* q1w3; const float* q1b3;
  const float* q2b2; const float* q2w3; const float* q2b3;
  float* out;
};

__global__ __launch_bounds__(ML_THR) void mlp_kernel(P1 P) {
  __shared__ __align__(16) unsigned short h1[ML_ROWS * H1S]; // 116,736 B
  __shared__ float xred[ML_ROWS * 4];                        //   4,096 B

  const int tid  = threadIdx.x;
  const int lane = tid & 63, w = tid >> 6;        // 16 waves
  const int rl = lane & 15, g = lane >> 4;

  const int rp = w & 7, ch = w >> 3;              // layer1: 8 row-groups x 2 nt-subsets
  const int wm = w >> 2, wn = w & 3;              // layer2: 4 x 64-row bands x 4 quarters

  // xum A-fragments: rows rp*32..+31 (B operand of swapped layer1)
  const unsigned short* xr0 = P.xum + ((size_t)blockIdx.x * ML_ROWS + rp * 32 + rl) * 64;
  const bf16x8 af0k0 = ld8(xr0 + g * 8);
  const bf16x8 af0k1 = ld8(xr0 + 32 + g * 8);
  const unsigned short* xr1 = xr0 + 16 * 64;
  const bf16x8 af1k0 = ld8(xr1 + g * 8);
  const bf16x8 af1k1 = ld8(xr1 + 32 + g * 8);

  for (int q = 0; q < 2; ++q) {
    f32x4 acc2[4][5];
    #pragma unroll
    for (int mt = 0; mt < 4; ++mt)
      #pragma unroll
      for (int jn = 0; jn < 5; ++jn) acc2[mt][jn] = (f32x4){0.f, 0.f, 0.f, 0.f};

    #pragma unroll
    for (int kh = 0; kh < 2; ++kh) {
      const int NTO  = kh ? 14 : 0;   // nt tile offset for this K-half
      const int HALF = kh ? 6 : 7;    // nt tiles per ch-subset
      const int KSO  = kh ? 7 : 0;    // global ks offset
      const int KSk  = kh ? 6 : 7;    // 32-wide k-steps this half

      // ---- layer1 (swapped): wave (rp,ch) -> 32 rows x HALF*16 cols ----
      for (int t = 0; t < HALF; ++t) {
        const int cnt = ch * HALF + t;            // col tile within half
        const int nt  = NTO + cnt;                // global w1 col tile
        const unsigned short* wf = P.img + ((size_t)(q * 312 + nt * 2)) * 512 + lane * 8;
        const bf16x8 b0 = ld8(wf);
        const bf16x8 b1 = ld8(wf + 512);
        f32x4 a = (f32x4){0.f, 0.f, 0.f, 0.f};
        f32x4 b = (f32x4){0.f, 0.f, 0.f, 0.f};
        a = MFMA(b0, af0k0, a); a = MFMA(b1, af0k1, a);
        b = MFMA(b0, af1k0, b); b = MFMA(b1, af1k1, b);
        const float a0 = fmaxf(a[0], 0.f), a1 = fmaxf(a[1], 0.f);
        const float a2 = fmaxf(a[2], 0.f), a3 = fmaxf(a[3], 0.f);
        const float c0 = fmaxf(b[0], 0.f), c1 = fmaxf(b[1], 0.f);
        const float c2 = fmaxf(b[2], 0.f), c3 = fmaxf(b[3], 0.f);
        unsigned int p01, p23, q01, q23;
        asm("v_cvt_pk_bf16_f32 %0, %1, %2" : "=v"(p01) : "v"(a0), "v"(a1));
        asm("v_cvt_pk_bf16_f32 %0, %1, %2" : "=v"(p23) : "v"(a2), "v"(a3));
        asm("v_cvt_pk_bf16_f32 %0, %1, %2" : "=v"(q01) : "v"(c0), "v"(c1));
        asm("v_cvt_pk_bf16_f32 %0, %1, %2" : "=v"(q23) : "v"(c2), "v"(c3));
        u32x2 pk; pk[0] = p01; pk[1] = p23;
        u32x2 qk; qk[0] = q01; qk[1] = q23;
        *(u32x2*)&h1[(size_t)(rp * 32 + rl) * H1S + cnt * 16 + g * 4]      = pk;
        *(u32x2*)&h1[(size_t)(rp * 32 + 16 + rl) * H1S + cnt * 16 + g * 4] = qk;
      }
      __syncthreads();                            // h1 half ready

      // ---- layer2: rows wm*64..+63 x cols wn*80..+79, this half's K ----
      {
        const unsigned short* w2f =
            P.img + ((size_t)(q * 312 + 52 + wn * 65)) * 512 + lane * 8;
        for (int ks = 0; ks < KSk; ++ks) {
          const int ksg = KSO + ks;
          bf16x8 am[4];
          #pragma unroll
          for (int mt = 0; mt < 4; ++mt)
            am[mt] = ld8(&h1[(size_t)(wm * 64 + mt * 16 + rl) * H1S + ks * 32 + g * 8]);
          #pragma unroll
          for (int jn = 0; jn < 5; ++jn) {
            const bf16x8 bf = ld8(w2f + (size_t)(jn * 13 + ksg) * 512);
            #pragma unroll
            for (int mt = 0; mt < 4; ++mt)
              acc2[mt][jn] = MFMA(am[mt], bf, acc2[mt][jn]);
          }
        }
      }
      __syncthreads();                            // h1 reads done; next half may overwrite
    }

    // ---- epilogue: x = sum_n relu(h2+b2)*w3 + b3 ----
    const float* b2p = q ? P.q2b2 : P.q1b2;
    const float* w3  = q ? P.q2w3 : P.q1w3;
    const float* b3  = q ? P.q2b3 : P.q1b3;
    float xp[4][4];
    #pragma unroll
    for (int mt = 0; mt < 4; ++mt)
      #pragma unroll
      for (int i = 0; i < 4; ++i) xp[mt][i] = 0.f;
    #pragma unroll
    for (int jn = 0; jn < 5; ++jn) {
      const int n = wn * 80 + jn * 16 + rl;
      if (n < 300) {
        const float bv = b2p[n], wv = w3[n];
        #pragma unroll
        for (int mt = 0; mt < 4; ++mt)
          #pragma unroll
          for (int i = 0; i < 4; ++i)
            xp[mt][i] += fmaxf(acc2[mt][jn][i] + bv, 0.f) * wv;
      }
    }
    #pragma unroll
    for (int off = 1; off < 16; off <<= 1)
      #pragma unroll
      for (int mt = 0; mt < 4; ++mt)
        #pragma unroll
        for (int i = 0; i < 4; ++i)
          xp[mt][i] += __shfl_xor(xp[mt][i], off, 64);
    if (rl == 0) {
      #pragma unroll
      for (int mt = 0; mt < 4; ++mt)
        #pragma unroll
        for (int i = 0; i < 4; ++i)
          xred[(wm * 64 + mt * 16 + g * 4 + i) * 4 + wn] = xp[mt][i];
    }
    __syncthreads();                              // xred visible
    if (tid < ML_ROWS) {
      const float4 xv = *(const float4*)&xred[tid * 4];
      P.out[(size_t)q * BTOT + (size_t)blockIdx.x * ML_ROWS + tid] =
          xv.x + xv.y + xv.z + xv.w + b3[0];
    }
    __syncthreads();                              // xred reads done before next q
  }
}

extern "C" void kernel_launch(void* const* d_in, const int* in_sizes, int n_in,
                              void* d_out, int out_size, void* d_ws, size_t ws_size,
                              hipStream_t stream) {
  (void)in_sizes; (void)n_in; (void)out_size; (void)ws_size;
  P0 A;
  A.state  = (const float*)d_in[0];
  A.action = (const float*)d_in[1];
  A.f1w = (const float*)d_in[2]; A.f1b = (const float*)d_in[3];
  A.f2w = (const float*)d_in[4]; A.f2b = (const float*)d_in[5];
  A.f3w = (const float*)d_in[6]; A.f3b = (const float*)d_in[7];
  A.q1w1 = (const float*)d_in[10]; A.q1b1 = (const float*)d_in[11]; A.q1w2 = (const float*)d_in[12];
  A.q2w1 = (const float*)d_in[16]; A.q2b1 = (const float*)d_in[17]; A.q2w2 = (const float*)d_in[18];
  A.ws  = (unsigned short*)d_ws;
  A.xum = (unsigned short*)((unsigned char*)d_ws + XUM_OFF);
  phase0_kernel<<<dim3(PK_BLK + PH_BLK), dim3(PH_THR), 0, stream>>>(A);

  P1 B;
  B.img  = (const unsigned short*)d_ws;
  B.xum  = (const unsigned short*)((unsigned char*)d_ws + XUM_OFF);
  B.q1b2 = (const float*)d_in[13]; B.q1w3 = (const float*)d_in[14]; B.q1b3 = (const float*)d_in[15];
  B.q2b2 = (const float*)d_in[19]; B.q2w3 = (const float*)d_in[20]; B.q2b3 = (const float*)d_in[21];
  B.out  = (float*)d_out;
  mlp_kernel<<<dim3(ML_BLK), dim3(ML_THR), 0, stream>>>(B);
}

// Round 19
// 104.339 us; speedup vs baseline: 1.4943x; 1.4943x over previous
//
#include <hip/hip_runtime.h>
#include <math.h>

// CriticGraphPolicy, MI355X (gfx950). Round 19 = Round 12 verbatim (best
// measured: 104.5us total; mlp 77.4us, phase0+pack ~27us).
// Final configuration after closing the optimization matrix:
//   fat-waves x 2/SIMD = 77us (this); fat x 4/SIMD impossible (reg file:
//   R14/R18 spill); thin x {2,4}/SIMD = 84/86us (R11/R15).
// Refuted for the residual: VALU(R10), latency(R11), bytes(R12), L2 path
// (R13-HOTW), LDS+barriers(R13-NOLDS), all memory(R13-PURE FETCH=0),
// TLP(R15), inst count(R16-32x32), phase0 blocking(R17).
// Structure: phase0_kernel (fused frag-pack + f32 feature MLP -> xum bf16),
// mlp_kernel (8 fat waves, barrier-free frag loads from L2, depth-2 reg
// pipeline, h1 in LDS stride 428 = conflict-free).

#define BTOT   65536
#define XUM_OFF 655360ull        // xum offset in d_ws (frag img = 638,976 B)

// phase0 (+fused pack)
#define PK_BLK  78
#define PH_THR  512
#define PH_ROWS 128
#define PH_BLK  (BTOT / PH_ROWS)
#define F1W 0
#define F1B 2112
#define F2W 2176
#define F2B 6272
#define F3W 6336
#define F3B 8384
#define W0_FLOATS 8416

// mlp
#define ML_THR  512              // 8 waves
#define ML_ROWS 128
#define ML_BLK  (BTOT / ML_ROWS)
#define H1S     428              // u16 stride: 856B rows -> 2-way banks

typedef float  f32x4 __attribute__((ext_vector_type(4)));
typedef __bf16 bf16x8 __attribute__((ext_vector_type(8)));
typedef unsigned short u16x8 __attribute__((ext_vector_type(8)));
typedef unsigned short u16x4 __attribute__((ext_vector_type(4)));
typedef unsigned int   u32x2 __attribute__((ext_vector_type(2)));

__device__ __forceinline__ unsigned short f2b(float f) {
  union { float f; unsigned int u; } v; v.f = f;
  return (unsigned short)((v.u + 0x7fffu + ((v.u >> 16) & 1u)) >> 16);
}
__device__ __forceinline__ float b2f(unsigned short u) {
  union { unsigned int u; float f; } v; v.u = ((unsigned int)u) << 16;
  return v.f;
}
__device__ __forceinline__ f32x4 MFMA(bf16x8 a, bf16x8 b, f32x4 c) {
  return __builtin_amdgcn_mfma_f32_16x16x32_bf16(a, b, c, 0, 0, 0);
}
__device__ __forceinline__ bf16x8 ld8(const unsigned short* p) {
  return __builtin_bit_cast(bf16x8, *(const u16x8*)p);
}
__device__ __forceinline__ float ftanh(float x) {
  float e = __builtin_amdgcn_exp2f(x * 2.885390081777927f);
  return (e - 1.0f) * __builtin_amdgcn_rcpf(e + 1.0f);
}

// ---------------- phase0 kernel (+fused fragment pack) ----------------
struct P0 {
  const float* state; const float* action;
  const float* f1w; const float* f1b;
  const float* f2w; const float* f2b;
  const float* f3w; const float* f3b;
  const float* q1w1; const float* q1b1; const float* q1w2;
  const float* q2w1; const float* q2b1; const float* q2w2;
  unsigned short* ws;
  unsigned short* xum;
};

__global__ __launch_bounds__(PH_THR, 4) void phase0_kernel(P0 P) {
  __shared__ float w0[W0_FLOATS];
  __shared__ unsigned short hx[PH_ROWS * 68];
  const int tid = threadIdx.x;

  if (blockIdx.x < PK_BLK) {          // fragment pack path
    const int gid = blockIdx.x * PH_THR + tid;
    const int lane = gid & 63, f = gid >> 6;
    const int q = f / 312, fl = f - q * 312;
    const float* w1 = q ? P.q2w1 : P.q1w1;
    const float* b1 = q ? P.q2b1 : P.q1b1;
    const float* w2 = q ? P.q2w2 : P.q1w2;
    int nt, ks; const bool isw1 = (fl < 52);
    if (isw1) { nt = fl >> 1; ks = fl & 1; }
    else      { int fl2 = fl - 52; nt = fl2 / 13; ks = fl2 - nt * 13; }
    const int col = nt * 16 + (lane & 15);
    const int k0  = ks * 32 + (lane >> 4) * 8;
    unsigned short v[8];
    #pragma unroll
    for (int j = 0; j < 8; ++j) {
      const int k = k0 + j;
      float x = 0.f;
      if (isw1) {
        if (col < 400) {
          if (k < 39) x = w1[(6 + k) * 400 + col];
          else if (k == 39) x = b1[col];
        }
      } else {
        if (k < 400 && col < 300) x = w2[k * 300 + col];
      }
      v[j] = f2b(x);
    }
    *(u16x8*)(P.ws + (size_t)f * 512 + lane * 8) = *(const u16x8*)v;
    return;
  }

  const int row = tid >> 2, sub = tid & 3, j0 = sub * 16;
  const long grow = (long)(blockIdx.x - PK_BLK) * PH_ROWS + row;

  for (int i = tid; i < 528;  i += PH_THR) *(f32x4*)(w0 + F1W + 4*i) = *(const f32x4*)(P.f1w + 4*i);
  for (int i = tid; i < 16;   i += PH_THR) *(f32x4*)(w0 + F1B + 4*i) = *(const f32x4*)(P.f1b + 4*i);
  for (int i = tid; i < 1024; i += PH_THR) *(f32x4*)(w0 + F2W + 4*i) = *(const f32x4*)(P.f2w + 4*i);
  for (int i = tid; i < 16;   i += PH_THR) *(f32x4*)(w0 + F2B + 4*i) = *(const f32x4*)(P.f2b + 4*i);
  for (int i = tid; i < 512;  i += PH_THR) *(f32x4*)(w0 + F3W + 4*i) = *(const f32x4*)(P.f3w + 4*i);
  for (int i = tid; i < 8;    i += PH_THR) *(f32x4*)(w0 + F3B + 4*i) = *(const f32x4*)(P.f3b + 4*i);

  float sa[33];
  {
    const float4* sp = (const float4*)(P.state + grow * 32);
    #pragma unroll
    for (int c = 0; c < 8; ++c) {
      float4 v = sp[c];
      sa[c*4+0] = v.x; sa[c*4+1] = v.y; sa[c*4+2] = v.z; sa[c*4+3] = v.w;
    }
    sa[32] = P.action[grow];
  }
  __syncthreads();

  float acc[16];
  #pragma unroll
  for (int j = 0; j < 16; ++j) acc[j] = w0[F1B + j0 + j];
  #pragma unroll 4
  for (int i = 0; i < 33; ++i) {
    const float s = sa[i];
    const f32x4* wr = (const f32x4*)&w0[F1W + i * 64 + j0];
    #pragma unroll
    for (int c = 0; c < 4; ++c) {
      f32x4 wv = wr[c];
      acc[c*4+0] += s * wv[0]; acc[c*4+1] += s * wv[1];
      acc[c*4+2] += s * wv[2]; acc[c*4+3] += s * wv[3];
    }
  }
  {
    float ss = 0.f;
    #pragma unroll
    for (int j = 0; j < 16; ++j) ss += acc[j] * acc[j];
    ss += __shfl_xor(ss, 1, 64); ss += __shfl_xor(ss, 2, 64);
    const float sc = 1.f / fmaxf(sqrtf(ss), 1e-12f);
    #pragma unroll
    for (int j = 0; j < 16; ++j) hx[row * 68 + j0 + j] = f2b(ftanh(acc[j] * sc));
  }
  __syncthreads();
  #pragma unroll
  for (int j = 0; j < 16; ++j) acc[j] = w0[F2B + j0 + j];
  #pragma unroll 4
  for (int i0 = 0; i0 < 16; ++i0) {
    const u16x4 hv4 = *(const u16x4*)&hx[row * 68 + i0 * 4];
    #pragma unroll
    for (int u = 0; u < 4; ++u) {
      const float hv = b2f(hv4[u]);
      const f32x4* wr = (const f32x4*)&w0[F2W + (i0 * 4 + u) * 64 + j0];
      #pragma unroll
      for (int c = 0; c < 4; ++c) {
        f32x4 wv = wr[c];
        acc[c*4+0] += hv * wv[0]; acc[c*4+1] += hv * wv[1];
        acc[c*4+2] += hv * wv[2]; acc[c*4+3] += hv * wv[3];
      }
    }
  }
  __syncthreads();
  #pragma unroll
  for (int j = 0; j < 16; ++j) hx[row * 68 + j0 + j] = f2b(ftanh(acc[j]));
  __syncthreads();
  const int j0m = sub * 8;
  float am[8];
  #pragma unroll
  for (int j = 0; j < 8; ++j) am[j] = w0[F3B + j0m + j];
  #pragma unroll 4
  for (int i0 = 0; i0 < 16; ++i0) {
    const u16x4 hv4 = *(const u16x4*)&hx[row * 68 + i0 * 4];
    #pragma unroll
    for (int u = 0; u < 4; ++u) {
      const float hv = b2f(hv4[u]);
      const f32x4* wr = (const f32x4*)&w0[F3W + (i0 * 4 + u) * 32 + j0m];
      #pragma unroll
      for (int c = 0; c < 2; ++c) {
        f32x4 wv = wr[c];
        am[c*4+0] += hv * wv[0]; am[c*4+1] += hv * wv[1];
        am[c*4+2] += hv * wv[2]; am[c*4+3] += hv * wv[3];
      }
    }
  }
  float sm = 0.f;
  #pragma unroll
  for (int j = 0; j < 8; ++j) sm += am[j] * am[j];
  sm += __shfl_xor(sm, 1, 64); sm += __shfl_xor(sm, 2, 64);
  const float scm = 1.f / fmaxf(sqrtf(sm), 1e-12f);
  __syncthreads();
  #pragma unroll
  for (int j = 0; j < 8; ++j) hx[row * 68 + j0m + j] = f2b(am[j] * scm);
  __syncthreads();
  {
    u16x8 v0, v1;
    #pragma unroll
    for (int t = 0; t < 16; ++t) {
      const int c = j0 + t;
      unsigned short u;
      if      (c < 3)  u = f2b(sa[c]);
      else if (c < 6)  u = f2b(sa[c - 3]);
      else if (c < 38) u = hx[row * 68 + (c - 6)];
      else if (c == 38) u = f2b(sa[32]);
      else if (c == 39) u = 0x3f80;
      else              u = 0;
      if (t < 8) v0[t] = u; else v1[t - 8] = u;
    }
    unsigned short* dst = P.xum + (size_t)grow * 64 + j0;
    *(u16x8*)dst = v0;
    *(u16x8*)(dst + 8) = v1;
  }
}

// ---------------- mlp kernel: 8 fat waves ----------------
struct P1 {
  const unsigned short* img; const unsigned short* xum;
  const float* q1b2; const float* q1w3; const float* q1b3;
  const float* q2b2; const float* q2w3; const float* q2b3;
  float* out;
};

__global__ __launch_bounds__(ML_THR, 2) void mlp_kernel(P1 P) {
  __shared__ __align__(16) unsigned short h1[ML_ROWS * H1S]; // 109,568 B
  __shared__ float xred[ML_ROWS * 4];

  const int tid  = threadIdx.x;
  const int lane = tid & 63, w = tid >> 6;        // 8 waves
  const int rl = lane & 15, g = lane >> 4;

  // layer1: wave -> row-tile pair rp (32 rows) x col-half ch (13 nt per q)
  const int rp = w & 3, ch = w >> 2;
  // layer2: wave -> 64-row band wm (4 mt) x 80-col quarter wn (5 jn)
  const int wm = w >> 2, wn = w & 3;

  // xum A-fragments for the 2 row-tiles
  const unsigned short* xr0 = P.xum + ((size_t)blockIdx.x * ML_ROWS + rp * 32 + rl) * 64;
  const bf16x8 af0k0 = ld8(xr0 + g * 8);
  const bf16x8 af0k1 = ld8(xr0 + 32 + g * 8);
  const unsigned short* xr1 = xr0 + 16 * 64;
  const bf16x8 af1k0 = ld8(xr1 + g * 8);
  const bf16x8 af1k1 = ld8(xr1 + 32 + g * 8);

  for (int q = 0; q < 2; ++q) {
    // ---- layer1 (swapped operands): 13 nt x 2 row-tiles, depth-2 pipeline --
    {
      const unsigned short* w1f = P.img + ((size_t)(q * 312 + ch * 26)) * 512 + lane * 8;
      unsigned short* h1w0 = &h1[(size_t)(rp * 32 + rl) * H1S + ch * 208 + g * 4];
      unsigned short* h1w1 = &h1[(size_t)(rp * 32 + 16 + rl) * H1S + ch * 208 + g * 4];
      bf16x8 wA0 = ld8(w1f + 0 * 512), wA1 = ld8(w1f + 1 * 512);
      bf16x8 wB0 = ld8(w1f + 2 * 512), wB1 = ld8(w1f + 3 * 512);
      for (int t = 0; t < 13; t += 2) {
        {
          f32x4 a = (f32x4){0.f, 0.f, 0.f, 0.f};
          f32x4 b = (f32x4){0.f, 0.f, 0.f, 0.f};
          a = MFMA(wA0, af0k0, a); a = MFMA(wA1, af0k1, a);
          b = MFMA(wA0, af1k0, b); b = MFMA(wA1, af1k1, b);
          if (t + 2 < 13) {
            wA0 = ld8(w1f + (size_t)((t + 2) * 2) * 512);
            wA1 = ld8(w1f + (size_t)((t + 2) * 2 + 1) * 512);
          }
          unsigned int p01, p23, q01, q23;
          const float a0 = fmaxf(a[0], 0.f), a1 = fmaxf(a[1], 0.f);
          const float a2 = fmaxf(a[2], 0.f), a3 = fmaxf(a[3], 0.f);
          const float b0 = fmaxf(b[0], 0.f), b1 = fmaxf(b[1], 0.f);
          const float b2 = fmaxf(b[2], 0.f), b3 = fmaxf(b[3], 0.f);
          asm("v_cvt_pk_bf16_f32 %0, %1, %2" : "=v"(p01) : "v"(a0), "v"(a1));
          asm("v_cvt_pk_bf16_f32 %0, %1, %2" : "=v"(p23) : "v"(a2), "v"(a3));
          asm("v_cvt_pk_bf16_f32 %0, %1, %2" : "=v"(q01) : "v"(b0), "v"(b1));
          asm("v_cvt_pk_bf16_f32 %0, %1, %2" : "=v"(q23) : "v"(b2), "v"(b3));
          u32x2 pk; pk[0] = p01; pk[1] = p23;
          u32x2 qk; qk[0] = q01; qk[1] = q23;
          *(u32x2*)(h1w0 + t * 16) = pk;
          *(u32x2*)(h1w1 + t * 16) = qk;
        }
        if (t + 1 < 13) {
          f32x4 a = (f32x4){0.f, 0.f, 0.f, 0.f};
          f32x4 b = (f32x4){0.f, 0.f, 0.f, 0.f};
          a = MFMA(wB0, af0k0, a); a = MFMA(wB1, af0k1, a);
          b = MFMA(wB0, af1k0, b); b = MFMA(wB1, af1k1, b);
          if (t + 3 < 13) {
            wB0 = ld8(w1f + (size_t)((t + 3) * 2) * 512);
            wB1 = ld8(w1f + (size_t)((t + 3) * 2 + 1) * 512);
          }
          unsigned int p01, p23, q01, q23;
          const float a0 = fmaxf(a[0], 0.f), a1 = fmaxf(a[1], 0.f);
          const float a2 = fmaxf(a[2], 0.f), a3 = fmaxf(a[3], 0.f);
          const float b0 = fmaxf(b[0], 0.f), b1 = fmaxf(b[1], 0.f);
          const float b2 = fmaxf(b[2], 0.f), b3 = fmaxf(b[3], 0.f);
          asm("v_cvt_pk_bf16_f32 %0, %1, %2" : "=v"(p01) : "v"(a0), "v"(a1));
          asm("v_cvt_pk_bf16_f32 %0, %1, %2" : "=v"(p23) : "v"(a2), "v"(a3));
          asm("v_cvt_pk_bf16_f32 %0, %1, %2" : "=v"(q01) : "v"(b0), "v"(b1));
          asm("v_cvt_pk_bf16_f32 %0, %1, %2" : "=v"(q23) : "v"(b2), "v"(b3));
          u32x2 pk; pk[0] = p01; pk[1] = p23;
          u32x2 qk; qk[0] = q01; qk[1] = q23;
          *(u32x2*)(h1w0 + (t + 1) * 16) = pk;
          *(u32x2*)(h1w1 + (t + 1) * 16) = qk;
        }
      }
    }
    __syncthreads();                              // h1 complete

    // ---- layer2: 4 mt x 5 jn x 13 ks; depth-2 pipelined B-frags ----
    f32x4 acc2[4][5];
    #pragma unroll
    for (int mt = 0; mt < 4; ++mt)
      #pragma unroll
      for (int jn = 0; jn < 5; ++jn) acc2[mt][jn] = (f32x4){0.f, 0.f, 0.f, 0.f};
    {
      const unsigned short* w2f = P.img + ((size_t)(q * 312 + 52 + wn * 65)) * 512 + lane * 8;
      bf16x8 bA[5], bB[5];
      #pragma unroll
      for (int jn = 0; jn < 5; ++jn) bA[jn] = ld8(w2f + (size_t)(jn * 13 + 0) * 512);
      #pragma unroll
      for (int jn = 0; jn < 5; ++jn) bB[jn] = ld8(w2f + (size_t)(jn * 13 + 1) * 512);
      for (int ks = 0; ks < 13; ks += 2) {
        {
          bf16x8 am[4];
          #pragma unroll
          for (int mt = 0; mt < 4; ++mt)
            am[mt] = ld8(&h1[(size_t)(wm * 64 + mt * 16 + rl) * H1S + ks * 32 + g * 8]);
          #pragma unroll
          for (int jn = 0; jn < 5; ++jn)
            #pragma unroll
            for (int mt = 0; mt < 4; ++mt)
              acc2[mt][jn] = MFMA(am[mt], bA[jn], acc2[mt][jn]);
          if (ks + 2 < 13) {
            #pragma unroll
            for (int jn = 0; jn < 5; ++jn)
              bA[jn] = ld8(w2f + (size_t)(jn * 13 + ks + 2) * 512);
          }
        }
        if (ks + 1 < 13) {
          bf16x8 am[4];
          #pragma unroll
          for (int mt = 0; mt < 4; ++mt)
            am[mt] = ld8(&h1[(size_t)(wm * 64 + mt * 16 + rl) * H1S + (ks + 1) * 32 + g * 8]);
          #pragma unroll
          for (int jn = 0; jn < 5; ++jn)
            #pragma unroll
            for (int mt = 0; mt < 4; ++mt)
              acc2[mt][jn] = MFMA(am[mt], bB[jn], acc2[mt][jn]);
          if (ks + 3 < 13) {
            #pragma unroll
            for (int jn = 0; jn < 5; ++jn)
              bB[jn] = ld8(w2f + (size_t)(jn * 13 + ks + 3) * 512);
          }
        }
      }
    }

    // ---- epilogue ----
    const float* b2p = q ? P.q2b2 : P.q1b2;
    const float* w3  = q ? P.q2w3 : P.q1w3;
    const float* b3  = q ? P.q2b3 : P.q1b3;
    float xp[4][4];
    #pragma unroll
    for (int mt = 0; mt < 4; ++mt)
      #pragma unroll
      for (int i = 0; i < 4; ++i) xp[mt][i] = 0.f;
    #pragma unroll
    for (int jn = 0; jn < 5; ++jn) {
      const int n = wn * 80 + jn * 16 + rl;
      if (n < 300) {
        const float bv = b2p[n], wv = w3[n];
        #pragma unroll
        for (int mt = 0; mt < 4; ++mt)
          #pragma unroll
          for (int i = 0; i < 4; ++i)
            xp[mt][i] += fmaxf(acc2[mt][jn][i] + bv, 0.f) * wv;
      }
    }
    #pragma unroll
    for (int off = 1; off < 16; off <<= 1)
      #pragma unroll
      for (int mt = 0; mt < 4; ++mt)
        #pragma unroll
        for (int i = 0; i < 4; ++i)
          xp[mt][i] += __shfl_xor(xp[mt][i], off, 64);
    if (rl == 0) {
      #pragma unroll
      for (int mt = 0; mt < 4; ++mt)
        #pragma unroll
        for (int i = 0; i < 4; ++i)
          xred[(wm * 64 + mt * 16 + g * 4 + i) * 4 + wn] = xp[mt][i];
    }
    __syncthreads();                              // xred visible; h1 reads done
    if (tid < ML_ROWS) {
      const float4 xv = *(const float4*)&xred[tid * 4];
      P.out[(size_t)q * BTOT + (size_t)blockIdx.x * ML_ROWS + tid] =
          xv.x + xv.y + xv.z + xv.w + b3[0];
    }
    __syncthreads();                              // xred read done; h1 reusable
  }
}

extern "C" void kernel_launch(void* const* d_in, const int* in_sizes, int n_in,
                              void* d_out, int out_size, void* d_ws, size_t ws_size,
                              hipStream_t stream) {
  (void)in_sizes; (void)n_in; (void)out_size; (void)ws_size;
  P0 A;
  A.state  = (const float*)d_in[0];
  A.action = (const float*)d_in[1];
  A.f1w = (const float*)d_in[2]; A.f1b = (const float*)d_in[3];
  A.f2w = (const float*)d_in[4]; A.f2b = (const float*)d_in[5];
  A.f3w = (const float*)d_in[6]; A.f3b = (const float*)d_in[7];
  A.q1w1 = (const float*)d_in[10]; A.q1b1 = (const float*)d_in[11]; A.q1w2 = (const float*)d_in[12];
  A.q2w1 = (const float*)d_in[16]; A.q2b1 = (const float*)d_in[17]; A.q2w2 = (const float*)d_in[18];
  A.ws  = (unsigned short*)d_ws;
  A.xum = (unsigned short*)((unsigned char*)d_ws + XUM_OFF);
  phase0_kernel<<<dim3(PK_BLK + PH_BLK), dim3(PH_THR), 0, stream>>>(A);

  P1 B;
  B.img  = (const unsigned short*)d_ws;
  B.xum  = (const unsigned short*)((unsigned char*)d_ws + XUM_OFF);
  B.q1b2 = (const float*)d_in[13]; B.q1w3 = (const float*)d_in[14]; B.q1b3 = (const float*)d_in[15];
  B.q2b2 = (const float*)d_in[19]; B.q2w3 = (const float*)d_in[20]; B.q2b3 = (const float*)d_in[21];
  B.out  = (float*)d_out;
  mlp_kernel<<<dim3(ML_BLK), dim3(ML_THR), 0, stream>>>(B);
}